// Round 7
// baseline (666.010 us; speedup 1.0000x reference)
//
#include <hip/hip_runtime.h>

typedef _Float16 half8 __attribute__((ext_vector_type(8)));
typedef _Float16 half4 __attribute__((ext_vector_type(4)));
typedef float    f32x4 __attribute__((ext_vector_type(4)));

#define MFMA32(a,b,c) __builtin_amdgcn_mfma_f32_16x16x32_f16(a,b,c,0,0,0)
#define MFMA16(a,b,c) __builtin_amdgcn_mfma_f32_16x16x16f16(a,b,c,0,0,0)

#if __has_builtin(__builtin_amdgcn_exp2f)
#define EXP2F(x) __builtin_amdgcn_exp2f(x)
#else
#define EXP2F(x) exp2f(x)
#endif

// Sb: per-wave-private S staging. [wv][G=n-pair][col=m 0..16][k=h+8*(n&1)]
// col stride 24 halves (48B, 16B-mult, bank-shifting), G stride 392, wv 3136.
#define SB(wv,G,col,k) ((wv)*3136 + (G)*392 + (col)*24 + (k))
// Wb: mixed weights. [g][n 0..16][m 0..64]; n stride 72, g stride 1160.
#define WB(g,n,m) ((g)*1160 + (n)*72 + (m))

// scale = DH^-0.5 = 1/8, folded together with log2(e) into Q so softmax uses exp2.
static constexpr float SCALE_LOG2E = 0.18033688011112042f;

static constexpr size_t QH_OFF = 0;
static constexpr size_t KH_OFF = (size_t)8  << 20;
static constexpr size_t VT_OFF = (size_t)16 << 20;
static constexpr size_t LS_OFF = (size_t)24 << 20;
static constexpr size_t O_OFF  = (size_t)25 << 20;
static constexpr size_t LPART  = (size_t)4*8*2048;       // floats per L partial
static constexpr size_t OPART  = (size_t)8192*512;       // halves per O partial

// ---------------------------------------------------------------------------
// K1: qkv projection. C[8192,1536] = X[8192,512] @ W[512,1536] + b.
// Scatters to Qh[b][h][n][64] (xSCALE_LOG2E), Kh[b][h][n][64], Vt[b][h][64][n], all f16.
// ---------------------------------------------------------------------------
__global__ __launch_bounds__(256)
void k_qkv(const float* __restrict__ x, const float* __restrict__ w,
           const float* __restrict__ bias, _Float16* __restrict__ Qh,
           _Float16* __restrict__ Kh, _Float16* __restrict__ Vt)
{
  __shared__ __align__(16) _Float16 Xs[64*40];
  __shared__ __align__(16) _Float16 Wt[64*40];
  const int tid = threadIdx.x;
  const int wv = tid >> 6, lane = tid & 63, l15 = lane & 15, qd = lane >> 4;
  const int row0 = blockIdx.x * 64, col0 = blockIdx.y * 64;

  const int xr = tid >> 2, xc = (tid & 3) * 8;
  const int wk = tid >> 3, wc = (tid & 7) * 8;

  f32x4 acc[4] = {{0.f,0.f,0.f,0.f},{0.f,0.f,0.f,0.f},{0.f,0.f,0.f,0.f},{0.f,0.f,0.f,0.f}};

  for (int k0 = 0; k0 < 512; k0 += 32) {
    f32x4 a0 = *(const f32x4*)(x + (size_t)(row0 + xr) * 512 + k0 + xc);
    f32x4 a1 = *(const f32x4*)(x + (size_t)(row0 + xr) * 512 + k0 + xc + 4);
    f32x4 b0 = *(const f32x4*)(w + (size_t)(k0 + wk) * 1536 + col0 + wc);
    f32x4 b1 = *(const f32x4*)(w + (size_t)(k0 + wk) * 1536 + col0 + wc + 4);
    half8 hx;
#pragma unroll
    for (int j = 0; j < 4; j++) { hx[j] = (_Float16)a0[j]; hx[j+4] = (_Float16)a1[j]; }
    *(half8*)&Xs[xr*40 + xc] = hx;
#pragma unroll
    for (int j = 0; j < 4; j++) {
      Wt[(wc+j  )*40 + wk] = (_Float16)b0[j];
      Wt[(wc+j+4)*40 + wk] = (_Float16)b1[j];
    }
    __syncthreads();
    half8 af = *(const half8*)&Xs[(wv*16 + l15)*40 + qd*8];
#pragma unroll
    for (int ct = 0; ct < 4; ct++) {
      half8 bf = *(const half8*)&Wt[(ct*16 + l15)*40 + qd*8];
      acc[ct] = MFMA32(af, bf, acc[ct]);
    }
    __syncthreads();
  }
#pragma unroll
  for (int ct = 0; ct < 4; ct++) {
    const int c = col0 + ct*16 + l15;
    const int sec = c >> 9, hh = (c >> 6) & 7, d = c & 63;
    const float bv = bias[c];
#pragma unroll
    for (int i = 0; i < 4; i++) {
      const int row = row0 + wv*16 + qd*4 + i;
      const int bb = row >> 11, n = row & 2047;
      float v = acc[ct][i] + bv;
      if (sec == 0)
        Qh[((size_t)((bb*8 + hh)*2048 + n))*64 + d] = (_Float16)(v * SCALE_LOG2E);
      else if (sec == 1)
        Kh[((size_t)((bb*8 + hh)*2048 + n))*64 + d] = (_Float16)v;
      else
        Vt[((size_t)((bb*8 + hh)*64 + d))*2048 + n] = (_Float16)v;
    }
  }
}

// ---------------------------------------------------------------------------
// K2: pass 1 — partial softmax denominators over an m-quarter.
// Q B-frags hoisted into registers (loop-invariant). (a) QK raw S -> Sb
// (wave-private); (b) th1-mix via MFMA16 blockdiag, exp2, accumulate.
// NO in-loop barriers. Grid 2048 = 128nt x (4b x 4mq).
// ---------------------------------------------------------------------------
__global__ __launch_bounds__(256, 3)
void k_pass1(const _Float16* __restrict__ Qh, const _Float16* __restrict__ Kh,
             const float* __restrict__ th1, float* __restrict__ Lsum)
{
  __shared__ __align__(16) _Float16 Sb[12544];   // 25088 B
  __shared__ float Lw[4][16][8];                 // 2048 B
  const int tid = threadIdx.x;
  const int wv = tid >> 6, lane = tid & 63, l15 = lane & 15, qd = lane >> 4;
  const int s = blockIdx.x & 15, nt = blockIdx.x >> 4;
  const int b = s >> 2, mq = s & 3;
  const int n0 = nt << 4;

  // A1-frag: blockdiag(th1, th1)
  half4 a1f;
#pragma unroll
  for (int j = 0; j < 4; j++)
    a1f[j] = ((l15 >> 3) == (qd >> 1)) ? (_Float16)th1[(l15 & 7)*8 + (qd & 1)*4 + j]
                                       : (_Float16)0.f;

  // hoisted Q B-frags (loop-invariant): 64 VGPRs
  half8 qf[8][2];
#pragma unroll
  for (int h = 0; h < 8; h++) {
    const _Float16* qp = Qh + ((size_t)((b*8+h)*2048 + n0 + l15))*64 + qd*8;
    qf[h][0] = *(const half8*)qp;
    qf[h][1] = *(const half8*)(qp + 32);
  }

  float lacc[8][4];
#pragma unroll
  for (int G = 0; G < 8; G++)
#pragma unroll
    for (int i = 0; i < 4; i++) lacc[G][i] = 0.f;

  for (int it = 0; it < 8; it++) {
    const int mmw = mq*512 + it*64 + wv*16;
    // (a) QK: A=K[m=l15][d], B=Q[d][n=l15] -> C[m=qd*4+i][n=l15]; pack h into hh
    half8 hh[4];
#pragma unroll
    for (int h = 0; h < 8; h++) {
      const _Float16* kp = Kh + ((size_t)((b*8+h)*2048 + mmw + l15))*64 + qd*8;
      half8 ka0 = *(const half8*)kp;
      half8 ka1 = *(const half8*)(kp + 32);
      f32x4 a = {0.f,0.f,0.f,0.f};
      a = MFMA32(ka0, qf[h][0], a);
      a = MFMA32(ka1, qf[h][1], a);
#pragma unroll
      for (int i = 0; i < 4; i++) hh[i][h] = (_Float16)a[i];
    }
#pragma unroll
    for (int i = 0; i < 4; i++)
      *(half8*)&Sb[SB(wv, l15 >> 1, qd*4 + i, (l15 & 1)*8)] = hh[i];

    // (b) mix1 + exp2 + accumulate (wave-private Sb; in-wave lgkm ordering)
#pragma unroll
    for (int G = 0; G < 8; G++) {
      half4 b1 = *(const half4*)&Sb[SB(wv, G, l15, qd*4)];
      f32x4 c1 = MFMA16(a1f, b1, ((f32x4){0.f,0.f,0.f,0.f}));
#pragma unroll
      for (int i = 0; i < 4; i++) lacc[G][i] += EXP2F(c1[i]);
    }
  }

  // reduce over m (l15 lanes hold m-cols), then across waves via LDS
#pragma unroll
  for (int G = 0; G < 8; G++)
#pragma unroll
    for (int i = 0; i < 4; i++) {
      float v = lacc[G][i];
      v += __shfl_xor(v, 1); v += __shfl_xor(v, 2);
      v += __shfl_xor(v, 4); v += __shfl_xor(v, 8);
      lacc[G][i] = v;
    }
  if (l15 == 0) {
#pragma unroll
    for (int G = 0; G < 8; G++)
#pragma unroll
      for (int i = 0; i < 4; i++)
        Lw[wv][G*2 + (qd >> 1)][(qd & 1)*4 + i] = lacc[G][i];
  }
  __syncthreads();
  if (tid < 128) {
    const int n = tid >> 3, g = tid & 7;
    float v = Lw[0][n][g] + Lw[1][n][g] + Lw[2][n][g] + Lw[3][n][g];
    Lsum[(size_t)mq*LPART + (size_t)(b*8 + g)*2048 + n0 + n] = v;
  }
}

// ---------------------------------------------------------------------------
// K3: pass 2 over an m-quarter. Q hoisted in regs. Loop rotated:
// (b) mix1(seeded)->exp2->mix2->Wb ; barrier ; [(c) PV  +  (a') QK for it+1]
// ; barrier — so next iter's K-load latency overlaps PV MFMAs.
// ---------------------------------------------------------------------------
__global__ __launch_bounds__(256, 3)
void k_pass2(const _Float16* __restrict__ Qh, const _Float16* __restrict__ Kh,
             const _Float16* __restrict__ Vt, const float* __restrict__ Lsum,
             const float* __restrict__ th1, const float* __restrict__ th2,
             _Float16* __restrict__ Obuf)
{
  __shared__ __align__(16) _Float16 Sb[12544];   // 25088 B
  __shared__ __align__(16) _Float16 Wb[9280];    // 18560 B
  __shared__ __align__(16) float nlgL[128];      // 512 B
  const int tid = threadIdx.x;
  const int wv = tid >> 6, lane = tid & 63, l15 = lane & 15, qd = lane >> 4;
  const int s = blockIdx.x & 15, nt = blockIdx.x >> 4;
  const int b = s >> 2, mq = s & 3;
  const int n0 = nt << 4;

  half4 a1f, b2f;
#pragma unroll
  for (int j = 0; j < 4; j++) {
    const bool diag = ((l15 >> 3) == (qd >> 1));
    a1f[j] = diag ? (_Float16)th1[(l15 & 7)*8 + (qd & 1)*4 + j] : (_Float16)0.f;
    b2f[j] = diag ? (_Float16)th2[(l15 & 7)*8 + (qd & 1)*4 + j] : (_Float16)0.f;
  }

  // nlg[n][g] = -log2(sum of 4 L partials)
  if (tid < 128) {
    const int n = tid >> 3, g = tid & 7;
    const size_t off = (size_t)(b*8 + g)*2048 + n0 + n;
    float l = Lsum[off] + Lsum[off + LPART] + Lsum[off + 2*LPART] + Lsum[off + 3*LPART];
    nlgL[n*8 + g] = -__log2f(l);
  }

  // hoisted Q B-frags (loop-invariant): 64 VGPRs
  half8 qf[8][2];
#pragma unroll
  for (int h = 0; h < 8; h++) {
    const _Float16* qp = Qh + ((size_t)((b*8+h)*2048 + n0 + l15))*64 + qd*8;
    qf[h][0] = *(const half8*)qp;
    qf[h][1] = *(const half8*)(qp + 32);
  }

  f32x4 og[2][4];
#pragma unroll
  for (int u = 0; u < 2; u++)
#pragma unroll
    for (int dt = 0; dt < 4; dt++)
      og[u][dt] = (f32x4){0.f,0.f,0.f,0.f};

  const _Float16* vbase = Vt + (size_t)(b*8)*64*2048;

  // (a) for it=0
  {
    const int mmw = mq*512 + wv*16;
    half8 hh[4];
#pragma unroll
    for (int h = 0; h < 8; h++) {
      const _Float16* kp = Kh + ((size_t)((b*8+h)*2048 + mmw + l15))*64 + qd*8;
      half8 ka0 = *(const half8*)kp;
      half8 ka1 = *(const half8*)(kp + 32);
      f32x4 a = {0.f,0.f,0.f,0.f};
      a = MFMA32(ka0, qf[h][0], a);
      a = MFMA32(ka1, qf[h][1], a);
#pragma unroll
      for (int i = 0; i < 4; i++) hh[i][h] = (_Float16)a[i];
    }
#pragma unroll
    for (int i = 0; i < 4; i++)
      *(half8*)&Sb[SB(wv, l15 >> 1, qd*4 + i, (l15 & 1)*8)] = hh[i];
  }
  __syncthreads();   // also covers nlgL

  for (int it = 0; it < 8; it++) {
    const int mm = mq*512 + it*64;

    // (b) mix1 (seeded with -log2 l in C) -> exp2 -> mix2 -> Wb
#pragma unroll
    for (int G = 0; G < 8; G++) {
      half4 b1 = *(const half4*)&Sb[SB(wv, G, l15, qd*4)];
      f32x4 cs = *(const f32x4*)&nlgL[(G*2 + (qd >> 1))*8 + (qd & 1)*4];
      f32x4 c1 = MFMA16(a1f, b1, cs);
      half4 a2;
#pragma unroll
      for (int i = 0; i < 4; i++) a2[i] = (_Float16)EXP2F(c1[i]);
      f32x4 c2 = MFMA16(a2, b2f, ((f32x4){0.f,0.f,0.f,0.f}));
      half4 w4;
#pragma unroll
      for (int i = 0; i < 4; i++) w4[i] = (_Float16)c2[i];
      *(half4*)&Wb[WB(l15 & 7, G*2 + (l15 >> 3), wv*16 + qd*4)] = w4;
    }
    __syncthreads();

    // (c) PV: wave handles g = 2wv, 2wv+1 over full 64 m; V direct from L2
#pragma unroll
    for (int u = 0; u < 2; u++) {
      const int g = wv*2 + u;
#pragma unroll
      for (int mc = 0; mc < 2; mc++) {
        half8 wf = *(const half8*)&Wb[WB(g, l15, mc*32 + qd*8)];
#pragma unroll
        for (int dt = 0; dt < 4; dt++) {
          half8 vb = *(const half8*)(vbase +
              (size_t)(g*64 + dt*16 + l15)*2048 + mm + mc*32 + qd*8);
          og[u][dt] = MFMA32(wf, vb, og[u][dt]);
        }
      }
    }

    // (a') QK for it+1 — same barrier region as (c): K latency overlaps PV.
    // Sb is wave-private; in-wave DS ordering makes the WAR with (b) safe.
    if (it < 7) {
      const int mmw = mm + 64 + wv*16;
      half8 hh[4];
#pragma unroll
      for (int h = 0; h < 8; h++) {
        const _Float16* kp = Kh + ((size_t)((b*8+h)*2048 + mmw + l15))*64 + qd*8;
        half8 ka0 = *(const half8*)kp;
        half8 ka1 = *(const half8*)(kp + 32);
        f32x4 a = {0.f,0.f,0.f,0.f};
        a = MFMA32(ka0, qf[h][0], a);
        a = MFMA32(ka1, qf[h][1], a);
#pragma unroll
        for (int i = 0; i < 4; i++) hh[i][h] = (_Float16)a[i];
      }
#pragma unroll
      for (int i = 0; i < 4; i++)
        *(half8*)&Sb[SB(wv, l15 >> 1, qd*4 + i, (l15 & 1)*8)] = hh[i];
    }
    __syncthreads();
  }

  // epilogue: og[u][dt][i] -> (n = n0+qd*4+i, col = (wv*2+u)*64 + dt*16 + l15)
  _Float16* Op = Obuf + (size_t)mq * OPART + ((size_t)(b*2048 + n0))*512;
#pragma unroll
  for (int u = 0; u < 2; u++)
#pragma unroll
    for (int dt = 0; dt < 4; dt++)
#pragma unroll
      for (int i = 0; i < 4; i++)
        Op[(size_t)(qd*4 + i)*512 + (wv*2+u)*64 + dt*16 + l15] = (_Float16)og[u][dt][i];
}

// ---------------------------------------------------------------------------
// K4: output projection summing 4 partial O buffers.
// out[8192,512] = (O0+O1+O2+O3) @ w_out[512,512] + b_out (fp32 out)
// ---------------------------------------------------------------------------
__global__ __launch_bounds__(256)
void k_oproj(const _Float16* __restrict__ Ob, const float* __restrict__ w,
             const float* __restrict__ bias, float* __restrict__ out)
{
  __shared__ __align__(16) _Float16 Xs[64*40];
  __shared__ __align__(16) _Float16 Wt[64*40];
  const int tid = threadIdx.x;
  const int wv = tid >> 6, lane = tid & 63, l15 = lane & 15, qd = lane >> 4;
  const int row0 = blockIdx.x * 64, col0 = blockIdx.y * 64;
  const int xr = tid >> 2, xc = (tid & 3) * 8;
  const int wk = tid >> 3, wc = (tid & 7) * 8;

  f32x4 acc[4] = {{0.f,0.f,0.f,0.f},{0.f,0.f,0.f,0.f},{0.f,0.f,0.f,0.f},{0.f,0.f,0.f,0.f}};

  for (int k0 = 0; k0 < 512; k0 += 32) {
    const size_t idx = (size_t)(row0 + xr)*512 + k0 + xc;
    half8 a0 = *(const half8*)(Ob + idx);
    half8 a1 = *(const half8*)(Ob + OPART + idx);
    half8 a2 = *(const half8*)(Ob + 2*OPART + idx);
    half8 a3 = *(const half8*)(Ob + 3*OPART + idx);
    *(half8*)&Xs[xr*40 + xc] = (a0 + a1) + (a2 + a3);
    f32x4 b0 = *(const f32x4*)(w + (size_t)(k0 + wk)*512 + col0 + wc);
    f32x4 b1 = *(const f32x4*)(w + (size_t)(k0 + wk)*512 + col0 + wc + 4);
#pragma unroll
    for (int j = 0; j < 4; j++) {
      Wt[(wc+j  )*40 + wk] = (_Float16)b0[j];
      Wt[(wc+j+4)*40 + wk] = (_Float16)b1[j];
    }
    __syncthreads();
    half8 af = *(const half8*)&Xs[(wv*16 + l15)*40 + qd*8];
#pragma unroll
    for (int ct = 0; ct < 4; ct++) {
      half8 bf = *(const half8*)&Wt[(ct*16 + l15)*40 + qd*8];
      acc[ct] = MFMA32(af, bf, acc[ct]);
    }
    __syncthreads();
  }
#pragma unroll
  for (int ct = 0; ct < 4; ct++) {
    const int c = col0 + ct*16 + l15;
    const float bv = bias[c];
#pragma unroll
    for (int i = 0; i < 4; i++) {
      const int row = row0 + wv*16 + qd*4 + i;
      out[(size_t)row*512 + c] = acc[ct][i] + bv;
    }
  }
}

// ---------------------------------------------------------------------------
extern "C" void kernel_launch(void* const* d_in, const int* in_sizes, int n_in,
                              void* d_out, int out_size, void* d_ws, size_t ws_size,
                              hipStream_t stream)
{
  (void)in_sizes; (void)n_in; (void)out_size;
  const float* x     = (const float*)d_in[0];
  const float* w_qkv = (const float*)d_in[1];
  const float* b_qkv = (const float*)d_in[2];
  const float* th1   = (const float*)d_in[3];
  const float* th2   = (const float*)d_in[4];
  const float* w_out = (const float*)d_in[5];
  const float* b_out = (const float*)d_in[6];
  float* out = (float*)d_out;

  char* ws = (char*)d_ws;
  _Float16* Qh   = (_Float16*)(ws + QH_OFF);
  _Float16* Kh   = (_Float16*)(ws + KH_OFF);
  _Float16* Vt   = (_Float16*)(ws + VT_OFF);
  float*    Lsum = (float*)   (ws + LS_OFF);
  _Float16* Obuf = (_Float16*)(ws + O_OFF);
  if (ws_size < ((size_t)58 << 20)) return;  // need 58 MB scratch

  k_qkv  <<<dim3(128, 24), 256, 0, stream>>>(x, w_qkv, b_qkv, Qh, Kh, Vt);
  k_pass1<<<dim3(2048),    256, 0, stream>>>(Qh, Kh, th1, Lsum);
  k_pass2<<<dim3(2048),    256, 0, stream>>>(Qh, Kh, Vt, Lsum, th1, th2, Obuf);
  k_oproj<<<dim3(128, 8),  256, 0, stream>>>(Obuf, w_out, b_out, out);
}

// Round 8
// 516.477 us; speedup vs baseline: 1.2895x; 1.2895x over previous
//
#include <hip/hip_runtime.h>

typedef _Float16 half8 __attribute__((ext_vector_type(8)));
typedef _Float16 half4 __attribute__((ext_vector_type(4)));
typedef float    f32x4 __attribute__((ext_vector_type(4)));

#define MFMA32(a,b,c) __builtin_amdgcn_mfma_f32_16x16x32_f16(a,b,c,0,0,0)
#define MFMA16(a,b,c) __builtin_amdgcn_mfma_f32_16x16x16f16(a,b,c,0,0,0)

#if __has_builtin(__builtin_amdgcn_exp2f)
#define EXP2F(x) __builtin_amdgcn_exp2f(x)
#else
#define EXP2F(x) exp2f(x)
#endif

// Q LDS: 128 rows x 64 halves, 8-half blocks XOR-swizzled by row.
#define LADDR(row, col8) ((((row)) << 6) + ((((col8) ^ ((row) & 7))) << 3))
// Sb: per-wave-private S staging. [wv][G=n-pair][col=m 0..16][k=h+8*(n&1)]
#define SB(wv,G,col,k) ((wv)*3136 + (G)*392 + (col)*24 + (k))
// Wb: mixed weights. [g][n 0..16][m 0..64]; n stride 72, g stride 1160.
#define WB(g,n,m) ((g)*1160 + (n)*72 + (m))

// scale = DH^-0.5 = 1/8, folded together with log2(e) into Q so softmax uses exp2.
static constexpr float SCALE_LOG2E = 0.18033688011112042f;

static constexpr size_t QH_OFF = 0;
static constexpr size_t KH_OFF = (size_t)8  << 20;
static constexpr size_t VT_OFF = (size_t)16 << 20;
static constexpr size_t O_OFF  = (size_t)24 << 20;

// ---------------------------------------------------------------------------
// K1: qkv projection. C[8192,1536] = X[8192,512] @ W[512,1536] + b.
// Scatters to Qh[b][h][n][64] (xSCALE_LOG2E), Kh[b][h][n][64], Vt[b][h][64][n], all f16.
// ---------------------------------------------------------------------------
__global__ __launch_bounds__(256)
void k_qkv(const float* __restrict__ x, const float* __restrict__ w,
           const float* __restrict__ bias, _Float16* __restrict__ Qh,
           _Float16* __restrict__ Kh, _Float16* __restrict__ Vt)
{
  __shared__ __align__(16) _Float16 Xs[64*40];
  __shared__ __align__(16) _Float16 Wt[64*40];
  const int tid = threadIdx.x;
  const int wv = tid >> 6, lane = tid & 63, l15 = lane & 15, qd = lane >> 4;
  const int row0 = blockIdx.x * 64, col0 = blockIdx.y * 64;

  const int xr = tid >> 2, xc = (tid & 3) * 8;
  const int wk = tid >> 3, wc = (tid & 7) * 8;

  f32x4 acc[4] = {{0.f,0.f,0.f,0.f},{0.f,0.f,0.f,0.f},{0.f,0.f,0.f,0.f},{0.f,0.f,0.f,0.f}};

  for (int k0 = 0; k0 < 512; k0 += 32) {
    f32x4 a0 = *(const f32x4*)(x + (size_t)(row0 + xr) * 512 + k0 + xc);
    f32x4 a1 = *(const f32x4*)(x + (size_t)(row0 + xr) * 512 + k0 + xc + 4);
    f32x4 b0 = *(const f32x4*)(w + (size_t)(k0 + wk) * 1536 + col0 + wc);
    f32x4 b1 = *(const f32x4*)(w + (size_t)(k0 + wk) * 1536 + col0 + wc + 4);
    half8 hx;
#pragma unroll
    for (int j = 0; j < 4; j++) { hx[j] = (_Float16)a0[j]; hx[j+4] = (_Float16)a1[j]; }
    *(half8*)&Xs[xr*40 + xc] = hx;
#pragma unroll
    for (int j = 0; j < 4; j++) {
      Wt[(wc+j  )*40 + wk] = (_Float16)b0[j];
      Wt[(wc+j+4)*40 + wk] = (_Float16)b1[j];
    }
    __syncthreads();
    half8 af = *(const half8*)&Xs[(wv*16 + l15)*40 + qd*8];
#pragma unroll
    for (int ct = 0; ct < 4; ct++) {
      half8 bf = *(const half8*)&Wt[(ct*16 + l15)*40 + qd*8];
      acc[ct] = MFMA32(af, bf, acc[ct]);
    }
    __syncthreads();
  }
#pragma unroll
  for (int ct = 0; ct < 4; ct++) {
    const int c = col0 + ct*16 + l15;
    const int sec = c >> 9, hh = (c >> 6) & 7, d = c & 63;
    const float bv = bias[c];
#pragma unroll
    for (int i = 0; i < 4; i++) {
      const int row = row0 + wv*16 + qd*4 + i;
      const int bb = row >> 11, n = row & 2047;
      float v = acc[ct][i] + bv;
      if (sec == 0)
        Qh[((size_t)((bb*8 + hh)*2048 + n))*64 + d] = (_Float16)(v * SCALE_LOG2E);
      else if (sec == 1)
        Kh[((size_t)((bb*8 + hh)*2048 + n))*64 + d] = (_Float16)v;
      else
        Vt[((size_t)((bb*8 + hh)*64 + d))*2048 + n] = (_Float16)v;
    }
  }
}

// ---------------------------------------------------------------------------
// K2: FUSED attention. Grid 512 = 128nt x 4b (blockIdx = nt*4 + b so each XCD
// works one b; its 2 MB K-slice stays L2-resident). Per block: 16 n-rows.
// Sweep 1 (no barriers): QK -> Sb (wave-private) -> mix1 MFMA16 -> exp2 ->
//   l accumulators; block-reduce -> nlgL in LDS (no global round-trip).
// Sweep 2: (b) mix1(seed=-log2 l in C) -> exp2 -> mix2 -> Wb ; bar ;
//   (c) PV (batched V loads) + (a') next QK (batched K loads) ; bar.
// All loads batched into register arrays to force memory-level parallelism
// (R7 lesson: compiler's minimal-VGPR allocation serializes loads otherwise).
// ---------------------------------------------------------------------------
__global__ __launch_bounds__(256, 2)
void k_attn(const _Float16* __restrict__ Qh, const _Float16* __restrict__ Kh,
            const _Float16* __restrict__ Vt, const float* __restrict__ th1,
            const float* __restrict__ th2, _Float16* __restrict__ Obuf)
{
  __shared__ __align__(16) _Float16 Qs[8192];    // 16384 B
  __shared__ __align__(16) _Float16 Sb[12544];   // 25088 B
  __shared__ __align__(16) _Float16 Wb[9280];    // 18560 B
  __shared__ float Lw[4][16][8];                 // 2048 B
  __shared__ float nlgL[128];                    // 512 B  (total 62592 B)
  const int tid = threadIdx.x;
  const int wv = tid >> 6, lane = tid & 63, l15 = lane & 15, qd = lane >> 4;
  const int b = blockIdx.x & 3, nt = blockIdx.x >> 2;
  const int n0 = nt << 4;

  // blockdiag A1 / B2 fragments for the 16x16x16 head-mix MFMAs
  half4 a1f, b2f;
#pragma unroll
  for (int j = 0; j < 4; j++) {
    const bool diag = ((l15 >> 3) == (qd >> 1));
    a1f[j] = diag ? (_Float16)th1[(l15 & 7)*8 + (qd & 1)*4 + j] : (_Float16)0.f;
    b2f[j] = diag ? (_Float16)th2[(l15 & 7)*8 + (qd & 1)*4 + j] : (_Float16)0.f;
  }

  // stage Q block: 8h x 16n x 64d (LDS: immune to rematerialization)
#pragma unroll
  for (int jj = 0; jj < 4; jj++) {
    const int c = tid + 256*jj;
    const int row = c >> 3, dc = c & 7;
    const int h = row >> 4, n = row & 15;
    *(half8*)&Qs[LADDR(row, dc)] =
      *(const half8*)(Qh + ((size_t)((b*8+h)*2048 + n0 + n))*64 + dc*8);
  }
  __syncthreads();

  const _Float16* kbase = Kh + (size_t)(b*8)*2048*64;
  const _Float16* vbase = Vt + (size_t)(b*8)*64*2048;

  // ---------------- Sweep 1: denominators ----------------
  float lacc[8][4];
#pragma unroll
  for (int G = 0; G < 8; G++)
#pragma unroll
    for (int i = 0; i < 4; i++) lacc[G][i] = 0.f;

  for (int it = 0; it < 32; it++) {
    const int mmw = it*64 + wv*16;
    half8 ka[8][2];                       // batched K loads (64 VGPRs in flight)
#pragma unroll
    for (int h = 0; h < 8; h++) {
      const _Float16* kp = kbase + ((size_t)(h*2048 + mmw + l15))*64 + qd*8;
      ka[h][0] = *(const half8*)kp;
      ka[h][1] = *(const half8*)(kp + 32);
    }
    half8 hh[4];
#pragma unroll
    for (int h = 0; h < 8; h++) {
      half8 qb0 = *(const half8*)&Qs[LADDR(h*16 + l15, qd)];
      half8 qb1 = *(const half8*)&Qs[LADDR(h*16 + l15, 4 + qd)];
      f32x4 a = {0.f,0.f,0.f,0.f};
      a = MFMA32(ka[h][0], qb0, a);
      a = MFMA32(ka[h][1], qb1, a);
#pragma unroll
      for (int i = 0; i < 4; i++) hh[i][h] = (_Float16)a[i];
    }
#pragma unroll
    for (int i = 0; i < 4; i++)
      *(half8*)&Sb[SB(wv, l15 >> 1, qd*4 + i, (l15 & 1)*8)] = hh[i];
#pragma unroll
    for (int G = 0; G < 8; G++) {
      half4 b1 = *(const half4*)&Sb[SB(wv, G, l15, qd*4)];
      f32x4 c1 = MFMA16(a1f, b1, ((f32x4){0.f,0.f,0.f,0.f}));
#pragma unroll
      for (int i = 0; i < 4; i++) lacc[G][i] += EXP2F(c1[i]);
    }
  }

  // reduce over m (l15 lanes), then across waves via LDS -> nlgL[n*8+g]
#pragma unroll
  for (int G = 0; G < 8; G++)
#pragma unroll
    for (int i = 0; i < 4; i++) {
      float v = lacc[G][i];
      v += __shfl_xor(v, 1); v += __shfl_xor(v, 2);
      v += __shfl_xor(v, 4); v += __shfl_xor(v, 8);
      lacc[G][i] = v;
    }
  if (l15 == 0) {
#pragma unroll
    for (int G = 0; G < 8; G++)
#pragma unroll
      for (int i = 0; i < 4; i++)
        Lw[wv][G*2 + (qd >> 1)][(qd & 1)*4 + i] = lacc[G][i];
  }
  __syncthreads();
  if (tid < 128) {
    const int n = tid >> 3, g = tid & 7;
    nlgL[n*8 + g] = -__log2f(Lw[0][n][g] + Lw[1][n][g] + Lw[2][n][g] + Lw[3][n][g]);
  }

  // ---------------- Sweep 2: PV ----------------
  f32x4 og[2][4];
#pragma unroll
  for (int u = 0; u < 2; u++)
#pragma unroll
    for (int dt = 0; dt < 4; dt++)
      og[u][dt] = (f32x4){0.f,0.f,0.f,0.f};

  // (a) prologue for it=0 (Sb wave-private)
  {
    const int mmw = wv*16;
    half8 ka[8][2];
#pragma unroll
    for (int h = 0; h < 8; h++) {
      const _Float16* kp = kbase + ((size_t)(h*2048 + mmw + l15))*64 + qd*8;
      ka[h][0] = *(const half8*)kp;
      ka[h][1] = *(const half8*)(kp + 32);
    }
    half8 hh[4];
#pragma unroll
    for (int h = 0; h < 8; h++) {
      half8 qb0 = *(const half8*)&Qs[LADDR(h*16 + l15, qd)];
      half8 qb1 = *(const half8*)&Qs[LADDR(h*16 + l15, 4 + qd)];
      f32x4 a = {0.f,0.f,0.f,0.f};
      a = MFMA32(ka[h][0], qb0, a);
      a = MFMA32(ka[h][1], qb1, a);
#pragma unroll
      for (int i = 0; i < 4; i++) hh[i][h] = (_Float16)a[i];
    }
#pragma unroll
    for (int i = 0; i < 4; i++)
      *(half8*)&Sb[SB(wv, l15 >> 1, qd*4 + i, (l15 & 1)*8)] = hh[i];
  }
  __syncthreads();   // covers nlgL (and prologue)

  for (int it = 0; it < 32; it++) {
    const int mm = it*64;

    // (b) mix1 (seeded) -> exp2 -> mix2 -> Wb
#pragma unroll
    for (int G = 0; G < 8; G++) {
      half4 b1 = *(const half4*)&Sb[SB(wv, G, l15, qd*4)];
      f32x4 cs = *(const f32x4*)&nlgL[(G*2 + (qd >> 1))*8 + (qd & 1)*4];
      f32x4 c1 = MFMA16(a1f, b1, cs);
      half4 a2;
#pragma unroll
      for (int i = 0; i < 4; i++) a2[i] = (_Float16)EXP2F(c1[i]);
      f32x4 c2 = MFMA16(a2, b2f, ((f32x4){0.f,0.f,0.f,0.f}));
      half4 w4;
#pragma unroll
      for (int i = 0; i < 4; i++) w4[i] = (_Float16)c2[i];
      *(half4*)&Wb[WB(l15 & 7, G*2 + (l15 >> 3), wv*16 + qd*4)] = w4;
    }
    __syncthreads();

    // (c) PV with batched V loads (16 in flight)
    half8 wf[2][2];
#pragma unroll
    for (int u = 0; u < 2; u++)
#pragma unroll
      for (int mc = 0; mc < 2; mc++)
        wf[u][mc] = *(const half8*)&Wb[WB(wv*2 + u, l15, mc*32 + qd*8)];
    half8 vb[2][2][4];
#pragma unroll
    for (int u = 0; u < 2; u++)
#pragma unroll
      for (int mc = 0; mc < 2; mc++)
#pragma unroll
        for (int dt = 0; dt < 4; dt++)
          vb[u][mc][dt] = *(const half8*)(vbase +
              (size_t)((wv*2+u)*64 + dt*16 + l15)*2048 + mm + mc*32 + qd*8);
#pragma unroll
    for (int u = 0; u < 2; u++)
#pragma unroll
      for (int mc = 0; mc < 2; mc++)
#pragma unroll
        for (int dt = 0; dt < 4; dt++)
          og[u][dt] = MFMA32(wf[u][mc], vb[u][mc][dt], og[u][dt]);

    // (a') QK for it+1 — K latency overlaps PV inside this barrier region
    if (it < 31) {
      const int mmw = mm + 64 + wv*16;
      half8 ka[8][2];
#pragma unroll
      for (int h = 0; h < 8; h++) {
        const _Float16* kp = kbase + ((size_t)(h*2048 + mmw + l15))*64 + qd*8;
        ka[h][0] = *(const half8*)kp;
        ka[h][1] = *(const half8*)(kp + 32);
      }
      half8 hh[4];
#pragma unroll
      for (int h = 0; h < 8; h++) {
        half8 qb0 = *(const half8*)&Qs[LADDR(h*16 + l15, qd)];
        half8 qb1 = *(const half8*)&Qs[LADDR(h*16 + l15, 4 + qd)];
        f32x4 a = {0.f,0.f,0.f,0.f};
        a = MFMA32(ka[h][0], qb0, a);
        a = MFMA32(ka[h][1], qb1, a);
#pragma unroll
        for (int i = 0; i < 4; i++) hh[i][h] = (_Float16)a[i];
      }
#pragma unroll
      for (int i = 0; i < 4; i++)
        *(half8*)&Sb[SB(wv, l15 >> 1, qd*4 + i, (l15 & 1)*8)] = hh[i];
    }
    __syncthreads();
  }

  // epilogue: og[u][dt][i] -> (n = n0+qd*4+i, col = (wv*2+u)*64 + dt*16 + l15)
  _Float16* Op = Obuf + ((size_t)(b*2048 + n0))*512;
#pragma unroll
  for (int u = 0; u < 2; u++)
#pragma unroll
    for (int dt = 0; dt < 4; dt++)
#pragma unroll
      for (int i = 0; i < 4; i++)
        Op[(size_t)(qd*4 + i)*512 + (wv*2+u)*64 + dt*16 + l15] = (_Float16)og[u][dt][i];
}

// ---------------------------------------------------------------------------
// K3: output projection. out[8192,512] = Obuf @ w_out[512,512] + b_out (fp32)
// ---------------------------------------------------------------------------
__global__ __launch_bounds__(256)
void k_oproj(const _Float16* __restrict__ Ob, const float* __restrict__ w,
             const float* __restrict__ bias, float* __restrict__ out)
{
  __shared__ __align__(16) _Float16 Xs[64*40];
  __shared__ __align__(16) _Float16 Wt[64*40];
  const int tid = threadIdx.x;
  const int wv = tid >> 6, lane = tid & 63, l15 = lane & 15, qd = lane >> 4;
  const int row0 = blockIdx.x * 64, col0 = blockIdx.y * 64;
  const int xr = tid >> 2, xc = (tid & 3) * 8;
  const int wk = tid >> 3, wc = (tid & 7) * 8;

  f32x4 acc[4] = {{0.f,0.f,0.f,0.f},{0.f,0.f,0.f,0.f},{0.f,0.f,0.f,0.f},{0.f,0.f,0.f,0.f}};

  for (int k0 = 0; k0 < 512; k0 += 32) {
    *(half8*)&Xs[xr*40 + xc] = *(const half8*)(Ob + (size_t)(row0 + xr)*512 + k0 + xc);
    f32x4 b0 = *(const f32x4*)(w + (size_t)(k0 + wk)*512 + col0 + wc);
    f32x4 b1 = *(const f32x4*)(w + (size_t)(k0 + wk)*512 + col0 + wc + 4);
#pragma unroll
    for (int j = 0; j < 4; j++) {
      Wt[(wc+j  )*40 + wk] = (_Float16)b0[j];
      Wt[(wc+j+4)*40 + wk] = (_Float16)b1[j];
    }
    __syncthreads();
    half8 af = *(const half8*)&Xs[(wv*16 + l15)*40 + qd*8];
#pragma unroll
    for (int ct = 0; ct < 4; ct++) {
      half8 bf = *(const half8*)&Wt[(ct*16 + l15)*40 + qd*8];
      acc[ct] = MFMA32(af, bf, acc[ct]);
    }
    __syncthreads();
  }
#pragma unroll
  for (int ct = 0; ct < 4; ct++) {
    const int c = col0 + ct*16 + l15;
    const float bv = bias[c];
#pragma unroll
    for (int i = 0; i < 4; i++) {
      const int row = row0 + wv*16 + qd*4 + i;
      out[(size_t)row*512 + c] = acc[ct][i] + bv;
    }
  }
}

// ---------------------------------------------------------------------------
extern "C" void kernel_launch(void* const* d_in, const int* in_sizes, int n_in,
                              void* d_out, int out_size, void* d_ws, size_t ws_size,
                              hipStream_t stream)
{
  (void)in_sizes; (void)n_in; (void)out_size;
  const float* x     = (const float*)d_in[0];
  const float* w_qkv = (const float*)d_in[1];
  const float* b_qkv = (const float*)d_in[2];
  const float* th1   = (const float*)d_in[3];
  const float* th2   = (const float*)d_in[4];
  const float* w_out = (const float*)d_in[5];
  const float* b_out = (const float*)d_in[6];
  float* out = (float*)d_out;

  char* ws = (char*)d_ws;
  _Float16* Qh   = (_Float16*)(ws + QH_OFF);
  _Float16* Kh   = (_Float16*)(ws + KH_OFF);
  _Float16* Vt   = (_Float16*)(ws + VT_OFF);
  _Float16* Obuf = (_Float16*)(ws + O_OFF);
  if (ws_size < ((size_t)33 << 20)) return;  // need 33 MB scratch

  k_qkv  <<<dim3(128, 24), 256, 0, stream>>>(x, w_qkv, b_qkv, Qh, Kh, Vt);
  k_attn <<<dim3(512),     256, 0, stream>>>(Qh, Kh, Vt, th1, th2, Obuf);
  k_oproj<<<dim3(128, 8),  256, 0, stream>>>(Obuf, w_out, b_out, out);
}